// Round 5
// baseline (372.700 us; speedup 1.0000x reference)
//
#include <hip/hip_runtime.h>

// ---------------------------------------------------------------------------
// SAGEEncoder: 2-layer GraphSAGE, N=100000, d=128, E=1.6M.
// Pipeline: prep (x->bf16 | weights->bf16 swizzled | bucket hist | last-block
// bucket scan, one launch) | binned scatter | per-bucket counting sort ->
// node-sorted CSR | per layer: FUSED gather+dual-GEMM (mean rows live in LDS,
// never round-trip HBM; weights read from L2-hot swizzled table).
// ---------------------------------------------------------------------------

using bf16x8 = __attribute__((ext_vector_type(8))) __bf16;
using f32x4  = __attribute__((ext_vector_type(4))) float;
using f32x2  = __attribute__((ext_vector_type(2))) float;

__device__ __forceinline__ unsigned short f2bf(float f) {
    __bf16 b = (__bf16)f;                       // RNE
    return __builtin_bit_cast(unsigned short, b);
}
__device__ __forceinline__ unsigned pk2(float a, float b) {
    return (unsigned)f2bf(a) | ((unsigned)f2bf(b) << 16);
}

// exclusive scan over 1024 threads (16 waves), ~2 barriers
__device__ __forceinline__ int exscan1024(int v, int* wsum, int t) {
    int lane = t & 63, w = t >> 6;
    int x = v;
#pragma unroll
    for (int s = 1; s < 64; s <<= 1) {
        int y = __shfl_up(x, s);
        if (lane >= s) x += y;
    }
    if (lane == 63) wsum[w] = x;
    __syncthreads();
    if (w == 0) {
        int ws = (lane < 16) ? wsum[lane] : 0;
#pragma unroll
        for (int s = 1; s < 16; s <<= 1) {
            int y = __shfl_up(ws, s);
            if (lane >= s) ws += y;
        }
        if (lane < 16) wsum[lane] = ws;          // inclusive wave sums
    }
    __syncthreads();
    int base = (w > 0) ? wsum[w - 1] : 0;
    return base + x - v;
}

// ---------------- prep: x->bf16 | weights swizzled | hist | scan ------------
// ghist[0..nb] must be zeroed before this kernel (ghist[nb] = ticket).
// The LAST histogram block (ticket) performs the bucket-base exclusive scan.

__global__ __launch_bounds__(256) void k_prep(
    const float4* __restrict__ x, uint4* __restrict__ xb8, int nvec, int ncvt,
    const float* __restrict__ W0, const float* __restrict__ W1,
    const float* __restrict__ W2, const float* __restrict__ W3,
    unsigned short* __restrict__ wsw, int ncvtw,
    const int* __restrict__ dst, int E, int* __restrict__ ghist, int nb, int nhist,
    int* __restrict__ gbase, int* __restrict__ gcur,
    int* __restrict__ row_start, int n)
{
    __shared__ int lh[800];
    const int b = blockIdx.x;
    if (b < ncvt) {
        int i = b * 256 + threadIdx.x;
        if (i >= nvec) return;
        float4 a = x[2 * i], c = x[2 * i + 1];
        uint4 o;
        o.x = pk2(a.x, a.y);
        o.y = pk2(a.z, a.w);
        o.z = pk2(c.x, c.y);
        o.w = pk2(c.z, c.w);
        xb8[i] = o;
    } else if (b < ncvt + ncvtw) {
        int id = (b - ncvt) * 256 + threadIdx.x;     // 65536 total
        int m = id >> 14, r = id & 16383;
        int c = r >> 7, k = r & 127;
        const float* W = (m == 0) ? W0 : (m == 1) ? W1 : (m == 2) ? W2 : W3;
        wsw[m * 16384 + c * 128 + (k ^ ((c & 7) << 3))] = f2bf(W[k * 128 + c]);
    } else {
        int hb = b - ncvt - ncvtw;
        for (int i = threadIdx.x; i < nb; i += 256) lh[i] = 0;
        __syncthreads();
        for (int e = hb * 256 + threadIdx.x; e < E; e += nhist * 256)
            atomicAdd(&lh[dst[e] >> 7], 1);
        __syncthreads();
        for (int i = threadIdx.x; i < nb; i += 256)
            if (lh[i]) atomicAdd(&ghist[i], lh[i]);

        // ----- last hist block does the scan -----
        __shared__ int winflag;
        __shared__ int swsum[4];
        if (threadIdx.x == 0) {
            __threadfence();                           // release our adds
            winflag = (atomicAdd(&ghist[nb], 1) == nhist - 1) ? 1 : 0;
        }
        __syncthreads();
        if (!winflag) return;
        __threadfence();                               // acquire all adds

        const int t = threadIdx.x, lane = t & 63, w = t >> 6;
        const int i0 = t * 4;                          // 1024 >= nb
        int v0 = (i0 + 0 < nb) ? __hip_atomic_load(&ghist[i0 + 0], __ATOMIC_RELAXED, __HIP_MEMORY_SCOPE_AGENT) : 0;
        int v1 = (i0 + 1 < nb) ? __hip_atomic_load(&ghist[i0 + 1], __ATOMIC_RELAXED, __HIP_MEMORY_SCOPE_AGENT) : 0;
        int v2 = (i0 + 2 < nb) ? __hip_atomic_load(&ghist[i0 + 2], __ATOMIC_RELAXED, __HIP_MEMORY_SCOPE_AGENT) : 0;
        int v3 = (i0 + 3 < nb) ? __hip_atomic_load(&ghist[i0 + 3], __ATOMIC_RELAXED, __HIP_MEMORY_SCOPE_AGENT) : 0;
        int s = v0 + v1 + v2 + v3;
        int xx = s;
#pragma unroll
        for (int sh = 1; sh < 64; sh <<= 1) {
            int y = __shfl_up(xx, sh);
            if (lane >= sh) xx += y;
        }
        if (lane == 63) swsum[w] = xx;
        __syncthreads();
        int base = 0;
        if (w > 0) base += swsum[0];
        if (w > 1) base += swsum[1];
        if (w > 2) base += swsum[2];
        int run = base + xx - s;
        if (i0 + 0 < nb) { gbase[i0 + 0] = run; gcur[i0 + 0] = run; } run += v0;
        if (i0 + 1 < nb) { gbase[i0 + 1] = run; gcur[i0 + 1] = run; } run += v1;
        if (i0 + 2 < nb) { gbase[i0 + 2] = run; gcur[i0 + 2] = run; } run += v2;
        if (i0 + 3 < nb) { gbase[i0 + 3] = run; gcur[i0 + 3] = run; }
        if (t == 0) { gbase[nb] = E; row_start[n] = E; }
    }
}

// ---------------- binned scatter (LDS-staged, sorted writes) ----------------
// packed word: (src << 7) | (dst & 127)

#define SC_CHUNK 8192

__global__ __launch_bounds__(1024) void k_binscatter(const int* __restrict__ src,
                                                     const int* __restrict__ dst, int E,
                                                     int* __restrict__ gcur,
                                                     unsigned* __restrict__ binned, int nb)
{
    __shared__ int lh[800];        // hist, then running cursor
    __shared__ int lbase[800];
    __shared__ int gb[800];
    __shared__ int wsum[16];
    __shared__ unsigned long long staged[SC_CHUNK];   // 64 KiB
    int t = threadIdx.x;
    int e0 = blockIdx.x * SC_CHUNK;
    if (e0 >= E) return;
    int ecnt = E - e0; if (ecnt > SC_CHUNK) ecnt = SC_CHUNK;

    for (int i = t; i < nb; i += 1024) lh[i] = 0;
    __syncthreads();
    for (int i = t; i < ecnt; i += 1024)
        atomicAdd(&lh[dst[e0 + i] >> 7], 1);
    __syncthreads();
    int v = (t < nb) ? lh[t] : 0;
    int excl = exscan1024(v, wsum, t);
    if (t < nb) {
        lbase[t] = excl;
        gb[t] = v ? atomicAdd(&gcur[t], v) : 0;
        lh[t] = excl;                       // running cursor
    }
    __syncthreads();
    for (int i = t; i < ecnt; i += 1024) {
        int d = dst[e0 + i], s = src[e0 + i];
        int b = d >> 7;
        int rank = atomicAdd(&lh[b], 1);
        unsigned pack = ((unsigned)s << 7) | (unsigned)(d & 127);
        unsigned gaddr = (unsigned)gb[b] + (unsigned)(rank - lbase[b]);
        staged[rank] = ((unsigned long long)gaddr << 32) | pack;
    }
    __syncthreads();
    for (int i = t; i < ecnt; i += 1024) {
        unsigned long long w = staged[i];
        binned[(unsigned)(w >> 32)] = (unsigned)w;
    }
}

// ---------------- per-bucket counting sort -> node-sorted CSR ---------------

#define BS_STAGE 8192

__global__ __launch_bounds__(256) void k_bucketsort(
    const unsigned* __restrict__ binned,
    const int* __restrict__ gbase,
    int* __restrict__ csr,
    int* __restrict__ row_start,
    float* __restrict__ inv_deg,
    int n)
{
    __shared__ int cnt[128];
    __shared__ int cur[128];
    __shared__ int wsum[4];
    __shared__ unsigned stg[BS_STAGE];     // 32 KiB
    const int t = threadIdx.x;
    const int b = blockIdx.x;
    const int beg = gbase[b], end = gbase[b + 1];
    const int len = end - beg;

    if (t < 128) cnt[t] = 0;
    __syncthreads();
    for (int i = beg + t; i < end; i += 256)
        atomicAdd(&cnt[binned[i] & 127], 1);
    __syncthreads();
    // exclusive scan over 128 counts (2 waves, shfl)
    int v = (t < 128) ? cnt[t] : 0;
    {
        int lane = t & 63, w = t >> 6;
        int x = v;
#pragma unroll
        for (int s = 1; s < 64; s <<= 1) {
            int y = __shfl_up(x, s);
            if (lane >= s) x += y;
        }
        if (lane == 63) wsum[w] = x;
        __syncthreads();
        int base = (w == 1) ? wsum[0] : (w == 2) ? wsum[0] + wsum[1]
                 : (w == 3) ? wsum[0] + wsum[1] + wsum[2] : 0;
        int excl = base + x - v;
        if (t < 128) {
            cur[t] = excl;
            int node = b * 128 + t;
            if (node < n) {
                row_start[node] = beg + excl;
                inv_deg[node] = 1.f / (float)max(v, 1);
            }
        }
    }
    __syncthreads();

    if (len <= BS_STAGE) {
        for (int i = beg + t; i < end; i += 256) {
            unsigned w = binned[i];
            int r = atomicAdd(&cur[w & 127], 1);
            stg[r] = w >> 7;
        }
        __syncthreads();
        for (int i = t; i < len; i += 256)
            csr[beg + i] = (int)stg[i];
    } else {   // overflow fallback (unreachable for this input)
        for (int i = beg + t; i < end; i += 256) {
            unsigned w = binned[i];
            int r = atomicAdd(&cur[w & 127], 1);
            csr[beg + r] = (int)(w >> 7);
        }
    }
}

// ---------------- fused gather + dual-GEMM (one kernel per layer) -----------
// Block = 128 nodes, 256 threads (4 waves). Phase 1: each wave gathers 32
// nodes (best-measured geometry: coalesced csr load + shfl-broadcast, 4-row
// dwordx4, quarter-split), writes mean rows bf16 into LDS (XOR-swizzled by
// row -> ~2-way bank conflict on fragment reads = free). Phase 2: dual-GEMM
// out[r][c] = act(mean[r]@W_l + feat[r]@W_r + bias); A1 from LDS, A2 = the
// block's own contiguous feat rows, B = L2-hot swizzled weight table (64 KB,
// shared by all blocks -> no per-block LDS staging). mean never touches HBM.

__device__ __forceinline__ f32x2 up2(unsigned x) {
    return (f32x2){__builtin_bit_cast(float, x << 16),
                   __builtin_bit_cast(float, x & 0xffff0000u)};
}
__device__ __forceinline__ void acc8(f32x2* a, uint4 v) {
    a[0] += up2(v.x);
    a[1] += up2(v.y);
    a[2] += up2(v.z);
    a[3] += up2(v.w);
}

template<bool RELU, bool OUTF32>
__global__ __launch_bounds__(256) void k_fused(
    const unsigned short* __restrict__ feat,
    const int* __restrict__ csr,
    const int* __restrict__ row_start,
    const float* __restrict__ inv_deg,
    const unsigned short* __restrict__ Wsw,
    const float* __restrict__ bias,
    void* __restrict__ outv,
    int n)
{
    __shared__ __align__(16) unsigned short Ml[128 * 128];   // 32 KiB mean tile
    const int lane = threadIdx.x & 63;
    const int wave = threadIdx.x >> 6;
    const int node0 = blockIdx.x * 128;

    // ---------------- phase 1: gather-mean into LDS ----------------
    {
        const int q  = lane >> 4;            // quarter: which of 4 rows per load
        const int cg = (lane & 15) << 3;     // column base (8 bf16 = 16 B / lane)
        const unsigned short* fp = feat + cg;
        for (int j = 0; j < 32; ++j) {
            const int nl = wave * 32 + j;
            const int node = node0 + nl;
            f32x2 a[4];
#pragma unroll
            for (int k = 0; k < 4; ++k) a[k] = (f32x2){0.f, 0.f};
            if (node < n) {
                const int beg = row_start[node], end = row_start[node + 1];
                for (int i = beg; i < end; i += 64) {
                    int cnt = end - i; if (cnt > 64) cnt = 64;
                    int idx = csr[i + (lane < cnt ? lane : cnt - 1)];
                    for (int e = 0; e < cnt; e += 16) {
                        const int r0 = e + q, r1 = e + 4 + q,
                                  r2 = e + 8 + q, r3 = e + 12 + q;
                        int s0 = __shfl(idx, r0 < cnt ? r0 : cnt - 1);
                        int s1 = __shfl(idx, r1 < cnt ? r1 : cnt - 1);
                        int s2 = __shfl(idx, r2 < cnt ? r2 : cnt - 1);
                        int s3 = __shfl(idx, r3 < cnt ? r3 : cnt - 1);
                        uint4 v0 = *(const uint4*)(fp + ((size_t)s0 << 7));
                        uint4 v1 = *(const uint4*)(fp + ((size_t)s1 << 7));
                        uint4 v2 = *(const uint4*)(fp + ((size_t)s2 << 7));
                        uint4 v3 = *(const uint4*)(fp + ((size_t)s3 << 7));
                        if (r0 < cnt) acc8(a, v0);
                        if (r1 < cnt) acc8(a, v1);
                        if (r2 < cnt) acc8(a, v2);
                        if (r3 < cnt) acc8(a, v3);
                    }
                }
            }
#pragma unroll
            for (int k = 0; k < 4; ++k) {
                a[k].x += __shfl_xor(a[k].x, 16);
                a[k].x += __shfl_xor(a[k].x, 32);
                a[k].y += __shfl_xor(a[k].y, 16);
                a[k].y += __shfl_xor(a[k].y, 32);
            }
            if (q == 0) {
                float w = (node < n) ? inv_deg[node] : 0.f;
                uint4 o;
                o.x = pk2(a[0].x * w, a[0].y * w);
                o.y = pk2(a[1].x * w, a[1].y * w);
                o.z = pk2(a[2].x * w, a[2].y * w);
                o.w = pk2(a[3].x * w, a[3].y * w);
                *(uint4*)(&Ml[nl * 128 + (cg ^ ((nl & 7) << 3))]) = o;
            }
        }
    }
    __syncthreads();

    // ---------------- phase 2: dual-GEMM ----------------
    const int lr = lane & 15;
    const int lg = lane >> 4;
    const int sw = (lr & 7) << 3;
    const int row0l = wave * 32;

    f32x4 acc[2][8];
#pragma unroll
    for (int m = 0; m < 2; ++m)
#pragma unroll
        for (int nn = 0; nn < 8; ++nn) acc[m][nn] = (f32x4){0.f, 0.f, 0.f, 0.f};

#pragma unroll
    for (int ks = 0; ks < 4; ++ks) {
        const int k0 = ks * 32 + lg * 8;
        bf16x8 a1[2], a2[2];
#pragma unroll
        for (int m = 0; m < 2; ++m) {
            const int rl = row0l + m * 16 + lr;
            a1[m] = *reinterpret_cast<const bf16x8*>(
                        &Ml[rl * 128 + (k0 ^ ((rl & 7) << 3))]);
            int r = node0 + rl;
            if (r >= n) r = n - 1;                     // clamp (stores masked)
            a2[m] = *reinterpret_cast<const bf16x8*>(feat + (size_t)r * 128 + k0);
        }
        const int kidx = k0 ^ sw;
#pragma unroll
        for (int nn = 0; nn < 8; ++nn) {
            const int c = nn * 16 + lr;
            bf16x8 b1 = *reinterpret_cast<const bf16x8*>(Wsw + c * 128 + kidx);
            bf16x8 b2 = *reinterpret_cast<const bf16x8*>(Wsw + 16384 + c * 128 + kidx);
#pragma unroll
            for (int m = 0; m < 2; ++m) {
                acc[m][nn] = __builtin_amdgcn_mfma_f32_16x16x32_bf16(a1[m], b1, acc[m][nn], 0, 0, 0);
                acc[m][nn] = __builtin_amdgcn_mfma_f32_16x16x32_bf16(a2[m], b2, acc[m][nn], 0, 0, 0);
            }
        }
    }

#pragma unroll
    for (int m = 0; m < 2; ++m) {
#pragma unroll
        for (int nn = 0; nn < 8; ++nn) {
            const int c = nn * 16 + lr;
            const float bv = bias[c];
#pragma unroll
            for (int i = 0; i < 4; ++i) {
                int r = node0 + row0l + m * 16 + lg * 4 + i;
                if (r < n) {
                    float v = acc[m][nn][i] + bv;
                    if (RELU) v = fmaxf(v, 0.f);
                    if (OUTF32)
                        ((float*)outv)[(size_t)r * 128 + c] = v;
                    else
                        ((unsigned short*)outv)[(size_t)r * 128 + c] = f2bf(v);
                }
            }
        }
    }
}

// ----------------------------- launcher ------------------------------------

extern "C" void kernel_launch(void* const* d_in, const int* in_sizes, int n_in,
                              void* d_out, int out_size, void* d_ws, size_t ws_size,
                              hipStream_t stream)
{
    const float* x   = (const float*)d_in[0];
    const int*   ei  = (const int*)d_in[1];
    const float* Wl0 = (const float*)d_in[2];
    const float* Wr0 = (const float*)d_in[3];
    const float* b0  = (const float*)d_in[4];
    const float* Wl1 = (const float*)d_in[5];
    const float* Wr1 = (const float*)d_in[6];
    const float* b1  = (const float*)d_in[7];
    float* out = (float*)d_out;

    const int n = in_sizes[0] / 128;      // 100000
    const int E = in_sizes[1] / 2;        // 1600000
    const int* src = ei;
    const int* dst = ei + E;
    const int nb = (n + 127) >> 7;        // 782 buckets

    char* ws = (char*)d_ws;
    size_t off = 0;
    auto alloc = [&](size_t sz) -> char* {
        char* p = ws + off;
        off += (sz + 1023) & ~(size_t)1023;
        return p;
    };
    unsigned short* xb     = (unsigned short*)alloc((size_t)n * 128 * 2);
    unsigned short* hbuf   = (unsigned short*)alloc((size_t)n * 128 * 2);  // layer-0 output
    unsigned*       binned = (unsigned*)      alloc((size_t)E * 4);
    int*            rs     = (int*)           alloc((size_t)(n + 1) * 4);
    float*          invd   = (float*)         alloc((size_t)n * 4);
    int*            ghist  = (int*)           alloc((size_t)(nb + 1) * 4);  // +ticket
    int*            gbase  = (int*)           alloc((size_t)(nb + 1) * 4);
    int*            gcur   = (int*)           alloc((size_t)nb * 4);
    unsigned short* wsw    = (unsigned short*)alloc(4 * 16384 * 2);
    int* csr;
    if (off + (size_t)E * 4 <= ws_size) csr = (int*)alloc((size_t)E * 4);
    else                                csr = (int*)binned;
    if (ws_size < off) return;

    const int nvec  = n * 128 / 8;        // 1.6M
    const int ncvt  = (nvec + 255) / 256; // 6250
    const int ncvtw = 256;
    const int nhist = 512;
    const int nsc   = (E + SC_CHUNK - 1) / SC_CHUNK;

    hipMemsetAsync(ghist, 0, (size_t)(nb + 1) * sizeof(int), stream);
    hipLaunchKernelGGL(k_prep, dim3(ncvt + ncvtw + nhist), dim3(256), 0, stream,
                       (const float4*)x, (uint4*)xb, nvec, ncvt,
                       Wl0, Wr0, Wl1, Wr1, wsw, ncvtw,
                       dst, E, ghist, nb, nhist,
                       gbase, gcur, rs, n);
    hipLaunchKernelGGL(k_binscatter, dim3(nsc),  dim3(1024), 0, stream,
                       src, dst, E, gcur, binned, nb);
    hipLaunchKernelGGL(k_bucketsort, dim3(nb),   dim3(256),  0, stream,
                       binned, gbase, csr, rs, invd, n);
    // layer 0: fused gather+GEMM, reads xb, writes h (bf16) -> hbuf
    hipLaunchKernelGGL((k_fused<true, false>), dim3(nb), dim3(256), 0, stream,
                       xb, csr, rs, invd, wsw, b0, (void*)hbuf, n);
    // layer 1: fused gather+GEMM, reads hbuf, writes f32 out
    hipLaunchKernelGGL((k_fused<false, true>), dim3(nb), dim3(256), 0, stream,
                       hbuf, csr, rs, invd, wsw + 2 * 16384, b1, (void*)out, n);
}